// Round 7
// baseline (58.703 us; speedup 1.0000x reference)
//
#include <hip/hip_runtime.h>

#define BSES 64
#define EDIM 128
#define HDIM 128
#define NTILE 32
#define TPB 512
#define KSCALE 2.8853900817779268f  // 2*log2(e): exp(2x) = exp2(KSCALE*x)

__device__ __forceinline__ float fexp2(float x) {
#if __has_builtin(__builtin_amdgcn_exp2f)
  return __builtin_amdgcn_exp2f(x);
#else
  return exp2f(x);
#endif
}
__device__ __forceinline__ float frcp(float x) {
#if __has_builtin(__builtin_amdgcn_rcpf)
  return __builtin_amdgcn_rcpf(x);
#else
  return 1.0f / x;
#endif
}

// et in-row bank-spread: h -> h + (h>>5) (proven conflict-free in R6).
__device__ __forceinline__ int etidx(int n, int h) {
  return n * 132 + h + (h >> 5);
}

// 4-way batched reciprocal sum: w0/x0 + w1/x1 + w2/x2 + w3/x3,
// x_j = fma(s_j, v_j, 1). 13 VALU + 1 rcp per 4 elements.
__device__ __forceinline__ float g4(float s0, float s1, float s2, float s3,
                                    float w0, float w1, float w2, float w3,
                                    float v0, float v1, float v2, float v3,
                                    float acc) {
  float x0 = fmaf(s0, v0, 1.f);
  float x1 = fmaf(s1, v1, 1.f);
  float x2 = fmaf(s2, v2, 1.f);
  float x3 = fmaf(s3, v3, 1.f);
  float p01 = x0 * x1, p23 = x2 * x3;
  float n01 = fmaf(w1, x0, w0 * x1);
  float n23 = fmaf(w3, x2, w2 * x3);
  float num = fmaf(n23, p01, n01 * p23);
  return fmaf(num, frcp(p01 * p23), acc);
}

// Session projection, GEMM-style (sess tile staged in LDS, coalesced W1 row
// loads). 2 blocks x 32 rows. esp4 packed: esp4[h4*64 + b*4 + (h&3)].
// Block 0 thread 0 additionally computes C = sum(W3) + b3.
__global__ __launch_bounds__(512) void taa_k1a(
    const float* __restrict__ sess, const float* __restrict__ W1,
    const float* __restrict__ b1, const float* __restrict__ W3,
    const float* __restrict__ b3, float* __restrict__ esp4,
    float* __restrict__ C_out) {
  __shared__ float sm[32][132];
  const int rb = blockIdx.x * 32;
  for (int k = threadIdx.x; k < 32 * 32; k += 512) {
    int r = k >> 5, c4 = k & 31;
    *(float4*)&sm[r][c4 * 4] = ((const float4*)(sess + (size_t)(rb + r) * EDIM))[c4];
  }
  __syncthreads();
  const int h4 = (threadIdx.x & 31) * 4;
  const int rg = threadIdx.x >> 5;  // 0..15 -> rows rg*2, rg*2+1
  float acc0[4] = {0.f, 0.f, 0.f, 0.f};
  float acc1[4] = {0.f, 0.f, 0.f, 0.f};
  for (int e = 0; e < EDIM; e += 4) {
    float4 w[4];
#pragma unroll
    for (int q = 0; q < 4; ++q)
      w[q] = *(const float4*)(W1 + (size_t)(e + q) * HDIM + h4);
    float4 em0 = *(const float4*)&sm[rg * 2 + 0][e];
    float4 em1 = *(const float4*)&sm[rg * 2 + 1][e];
#pragma unroll
    for (int q = 0; q < 4; ++q) {
      float e0 = q == 0 ? em0.x : q == 1 ? em0.y : q == 2 ? em0.z : em0.w;
      float e1 = q == 0 ? em1.x : q == 1 ? em1.y : q == 2 ? em1.z : em1.w;
      acc0[0] = fmaf(e0, w[q].x, acc0[0]);
      acc0[1] = fmaf(e0, w[q].y, acc0[1]);
      acc0[2] = fmaf(e0, w[q].z, acc0[2]);
      acc0[3] = fmaf(e0, w[q].w, acc0[3]);
      acc1[0] = fmaf(e1, w[q].x, acc1[0]);
      acc1[1] = fmaf(e1, w[q].y, acc1[1]);
      acc1[2] = fmaf(e1, w[q].z, acc1[2]);
      acc1[3] = fmaf(e1, w[q].w, acc1[3]);
    }
  }
  float4 bb = *(const float4*)(b1 + h4);
  const int b0 = rb + rg * 2;
  float4 o0, o1;
  o0.x = fexp2((acc0[0] + bb.x) * KSCALE);
  o0.y = fexp2((acc0[1] + bb.y) * KSCALE);
  o0.z = fexp2((acc0[2] + bb.z) * KSCALE);
  o0.w = fexp2((acc0[3] + bb.w) * KSCALE);
  o1.x = fexp2((acc1[0] + bb.x) * KSCALE);
  o1.y = fexp2((acc1[1] + bb.y) * KSCALE);
  o1.z = fexp2((acc1[2] + bb.z) * KSCALE);
  o1.w = fexp2((acc1[3] + bb.w) * KSCALE);
  *(float4*)&esp4[h4 * 64 + (b0 + 0) * 4] = o0;
  *(float4*)&esp4[h4 * 64 + (b0 + 1) * 4] = o1;
  if (blockIdx.x == 0 && threadIdx.x == 0) {
    float s = b3[0];
    for (int i = 0; i < HDIM; ++i) s += W3[i];
    *C_out = s;
  }
}

// Fused per 32-target tile, 512 threads (8 waves), forced-ILP version.
// P1: emb tile + w3 -> LDS. P2: GEMM (pipelined W2 prefetch) + exp2 -> et.
// P3: lane = session; wave w -> targets nb+4w..+3; esp in REGISTERS per
// 32-h quarter (8 coalesced dwordx4, one wait per 8 iters); w3/et via
// uniform LDS broadcast; inner 8 fully unrolled, 4 independent g4 chains.
// score[b][n] = C - 2 * sum_h w3[h] * rcp(fma(esp[b][h], etp[n][h], 1))
__global__ __launch_bounds__(512, 4) void taa_fused(
    const float* __restrict__ emb, const float* __restrict__ W2,
    const float* __restrict__ b2, const float* __restrict__ esp4,
    const float* __restrict__ w3, const float* __restrict__ Cptr,
    float* __restrict__ out, int N) {
  __shared__ float sm[NTILE][132];   // emb tile
  __shared__ float et[NTILE * 132];  // exp2(tp'), bank-spread rows
  __shared__ float w3s[HDIM];
  const int nb = blockIdx.x * NTILE;

  // Phase 1: stage emb tile + w3.
  for (int k = threadIdx.x; k < NTILE * 32; k += TPB) {
    int r = k >> 5, c4 = k & 31;
    float4 v = make_float4(0.f, 0.f, 0.f, 0.f);
    if (nb + r < N) v = ((const float4*)(emb + (size_t)(nb + r) * EDIM))[c4];
    *(float4*)&sm[r][c4 * 4] = v;
  }
  if (threadIdx.x < HDIM) w3s[threadIdx.x] = w3[threadIdx.x];
  __syncthreads();

  // Phase 2: GEMM + exp2 + et write, software-pipelined W2 prefetch.
  {
    const int h4 = (threadIdx.x & 31) * 4;
    const int rg = threadIdx.x >> 5;  // 0..15
    float acc0[4] = {0.f, 0.f, 0.f, 0.f};
    float acc1[4] = {0.f, 0.f, 0.f, 0.f};
    float4 wa[4], wb[4];
#pragma unroll
    for (int q = 0; q < 4; ++q)
      wa[q] = *(const float4*)(W2 + (size_t)q * HDIM + h4);
#pragma unroll 2
    for (int e = 0; e < EDIM; e += 4) {
      if (e + 4 < EDIM) {
#pragma unroll
        for (int q = 0; q < 4; ++q)
          wb[q] = *(const float4*)(W2 + (size_t)(e + 4 + q) * HDIM + h4);
      }
      float4 em0 = *(const float4*)&sm[rg * 2 + 0][e];
      float4 em1 = *(const float4*)&sm[rg * 2 + 1][e];
      acc0[0] = fmaf(em0.x, wa[0].x, acc0[0]);
      acc0[1] = fmaf(em0.x, wa[0].y, acc0[1]);
      acc0[2] = fmaf(em0.x, wa[0].z, acc0[2]);
      acc0[3] = fmaf(em0.x, wa[0].w, acc0[3]);
      acc1[0] = fmaf(em1.x, wa[0].x, acc1[0]);
      acc1[1] = fmaf(em1.x, wa[0].y, acc1[1]);
      acc1[2] = fmaf(em1.x, wa[0].z, acc1[2]);
      acc1[3] = fmaf(em1.x, wa[0].w, acc1[3]);
      acc0[0] = fmaf(em0.y, wa[1].x, acc0[0]);
      acc0[1] = fmaf(em0.y, wa[1].y, acc0[1]);
      acc0[2] = fmaf(em0.y, wa[1].z, acc0[2]);
      acc0[3] = fmaf(em0.y, wa[1].w, acc0[3]);
      acc1[0] = fmaf(em1.y, wa[1].x, acc1[0]);
      acc1[1] = fmaf(em1.y, wa[1].y, acc1[1]);
      acc1[2] = fmaf(em1.y, wa[1].z, acc1[2]);
      acc1[3] = fmaf(em1.y, wa[1].w, acc1[3]);
      acc0[0] = fmaf(em0.z, wa[2].x, acc0[0]);
      acc0[1] = fmaf(em0.z, wa[2].y, acc0[1]);
      acc0[2] = fmaf(em0.z, wa[2].z, acc0[2]);
      acc0[3] = fmaf(em0.z, wa[2].w, acc0[3]);
      acc1[0] = fmaf(em1.z, wa[2].x, acc1[0]);
      acc1[1] = fmaf(em1.z, wa[2].y, acc1[1]);
      acc1[2] = fmaf(em1.z, wa[2].z, acc1[2]);
      acc1[3] = fmaf(em1.z, wa[2].w, acc1[3]);
      acc0[0] = fmaf(em0.w, wa[3].x, acc0[0]);
      acc0[1] = fmaf(em0.w, wa[3].y, acc0[1]);
      acc0[2] = fmaf(em0.w, wa[3].z, acc0[2]);
      acc0[3] = fmaf(em0.w, wa[3].w, acc0[3]);
      acc1[0] = fmaf(em1.w, wa[3].x, acc1[0]);
      acc1[1] = fmaf(em1.w, wa[3].y, acc1[1]);
      acc1[2] = fmaf(em1.w, wa[3].z, acc1[2]);
      acc1[3] = fmaf(em1.w, wa[3].w, acc1[3]);
#pragma unroll
      for (int q = 0; q < 4; ++q) wa[q] = wb[q];
    }
    float4 bb2 = *(const float4*)(b2 + h4);
    const int nr0 = rg * 2;
    float4 o0, o1;
    o0.x = fexp2((acc0[0] + bb2.x) * KSCALE);
    o0.y = fexp2((acc0[1] + bb2.y) * KSCALE);
    o0.z = fexp2((acc0[2] + bb2.z) * KSCALE);
    o0.w = fexp2((acc0[3] + bb2.w) * KSCALE);
    o1.x = fexp2((acc1[0] + bb2.x) * KSCALE);
    o1.y = fexp2((acc1[1] + bb2.y) * KSCALE);
    o1.z = fexp2((acc1[2] + bb2.z) * KSCALE);
    o1.w = fexp2((acc1[3] + bb2.w) * KSCALE);
    *(float4*)&et[etidx(nr0 + 0, h4)] = o0;  // conflict-free (bank-spread)
    *(float4*)&et[etidx(nr0 + 1, h4)] = o1;
  }
  __syncthreads();

  // Phase 3: scoring. lane = session; wave w -> targets nb+4w..+3.
  const int lane = threadIdx.x & 63;
  const int wv = threadIdx.x >> 6;  // 0..7
  const int n0 = nb + wv * 4;
  const float* espl = esp4 + (lane << 2);
  const int t0 = wv * 4;
  float sacc0 = 0.f, sacc1 = 0.f, sacc2 = 0.f, sacc3 = 0.f;
#pragma unroll 1
  for (int q = 0; q < 4; ++q) {
    float4 se[8];
#pragma unroll
    for (int k = 0; k < 8; ++k)
      se[k] = *(const float4*)(espl + (((q << 3) + k) << 8));  // coalesced 1KB
#pragma unroll
    for (int k = 0; k < 8; ++k) {
      const int hg = (q << 3) + k;
      float4 wv4 = *(const float4*)&w3s[hg << 2];               // uniform LDS
      float4 v0 = *(const float4*)&et[etidx(t0 + 0, hg << 2)];  // uniform LDS
      float4 v1 = *(const float4*)&et[etidx(t0 + 1, hg << 2)];
      float4 v2 = *(const float4*)&et[etidx(t0 + 2, hg << 2)];
      float4 v3 = *(const float4*)&et[etidx(t0 + 3, hg << 2)];
      sacc0 = g4(se[k].x, se[k].y, se[k].z, se[k].w, wv4.x, wv4.y, wv4.z, wv4.w,
                 v0.x, v0.y, v0.z, v0.w, sacc0);
      sacc1 = g4(se[k].x, se[k].y, se[k].z, se[k].w, wv4.x, wv4.y, wv4.z, wv4.w,
                 v1.x, v1.y, v1.z, v1.w, sacc1);
      sacc2 = g4(se[k].x, se[k].y, se[k].z, se[k].w, wv4.x, wv4.y, wv4.z, wv4.w,
                 v2.x, v2.y, v2.z, v2.w, sacc2);
      sacc3 = g4(se[k].x, se[k].y, se[k].z, se[k].w, wv4.x, wv4.y, wv4.z, wv4.w,
                 v3.x, v3.y, v3.z, v3.w, sacc3);
    }
  }
  const float Cv = *Cptr;  // uniform -> s_load
  float4 res;
  res.x = fmaf(-2.f, sacc0, Cv);
  res.y = fmaf(-2.f, sacc1, Cv);
  res.z = fmaf(-2.f, sacc2, Cv);
  res.w = fmaf(-2.f, sacc3, Cv);
  if (n0 + 3 < N) {
    *(float4*)(out + (size_t)lane * N + n0) = res;
  } else {
    float r4[4] = {res.x, res.y, res.z, res.w};
    for (int i = 0; i < 4 && n0 + i < N; ++i) out[(size_t)lane * N + n0 + i] = r4[i];
  }
}

extern "C" void kernel_launch(void* const* d_in, const int* in_sizes, int n_in,
                              void* d_out, int out_size, void* d_ws, size_t ws_size,
                              hipStream_t stream) {
  const float* sess = (const float*)d_in[0];
  const float* emb  = (const float*)d_in[1];
  const float* W1   = (const float*)d_in[2];
  const float* b1   = (const float*)d_in[3];
  const float* W2   = (const float*)d_in[4];
  const float* b2   = (const float*)d_in[5];
  const float* W3   = (const float*)d_in[6];
  const float* b3   = (const float*)d_in[7];
  float* out = (float*)d_out;
  const int N = in_sizes[1] / EDIM;   // 20000

  float* esp4 = (float*)d_ws;                     // B*128 floats (packed)
  float* Cp   = esp4 + (size_t)BSES * HDIM;       // 1 float

  taa_k1a<<<2, 512, 0, stream>>>(sess, W1, b1, W3, b3, esp4, Cp);
  taa_fused<<<(N + NTILE - 1) / NTILE, TPB, 0, stream>>>(emb, W2, b2, esp4, W3, Cp, out, N);
}

// Round 8
// 47.113 us; speedup vs baseline: 1.2460x; 1.2460x over previous
//
#include <hip/hip_runtime.h>

#define BSES 64
#define EDIM 128
#define HDIM 128
#define KSCALE 2.8853900817779268f  // 2*log2(e): exp(2x) = exp2(KSCALE*x)

__device__ __forceinline__ float fexp2(float x) {
#if __has_builtin(__builtin_amdgcn_exp2f)
  return __builtin_amdgcn_exp2f(x);
#else
  return exp2f(x);
#endif
}
__device__ __forceinline__ float frcp(float x) {
#if __has_builtin(__builtin_amdgcn_rcpf)
  return __builtin_amdgcn_rcpf(x);
#else
  return 1.0f / x;
#endif
}

// 4-way batched reciprocal sum: w0/x0 + w1/x1 + w2/x2 + w3/x3,
// x_j = fma(s_j, v_j, 1). 13 VALU + 1 rcp per 4 elements. (Proven R3+.)
__device__ __forceinline__ float g4(float s0, float s1, float s2, float s3,
                                    float w0, float w1, float w2, float w3,
                                    float4 v, float acc) {
  float x0 = fmaf(s0, v.x, 1.f);
  float x1 = fmaf(s1, v.y, 1.f);
  float x2 = fmaf(s2, v.z, 1.f);
  float x3 = fmaf(s3, v.w, 1.f);
  float p01 = x0 * x1, p23 = x2 * x3;
  float n01 = fmaf(w1, x0, w0 * x1);
  float n23 = fmaf(w3, x2, w2 * x3);
  float num = fmaf(n23, p01, n01 * p23);
  return fmaf(num, frcp(p01 * p23), acc);
}

// Fused projections (R3-proven shape). Blocks [0,nbTP): tp-projection,
// 32 targets each, output TRANSPOSED-PACKED: etpT4[hq][n][4] (plane stride
// npad). Blocks [nbTP,..): esp[b][h] = exp2((sess·W1+b1)*K), natural layout
// (k2 s_loads rows); plus C = sum(W3)+b3.
__global__ __launch_bounds__(256) void taa_k1(
    const float* __restrict__ sess, const float* __restrict__ W1,
    const float* __restrict__ b1, const float* __restrict__ emb,
    const float* __restrict__ W2, const float* __restrict__ b2,
    const float* __restrict__ W3, const float* __restrict__ b3,
    float* __restrict__ etpT4, float* __restrict__ esp,
    float* __restrict__ C_out, int N, int npad, int nbTP) {
  if ((int)blockIdx.x < nbTP) {
    __shared__ float sm[32][132];  // emb tile, padded stride
    const int nb = blockIdx.x * 32;
    for (int k = threadIdx.x; k < 32 * 32; k += 256) {
      int r = k >> 5, c4 = k & 31;
      float4 v = make_float4(0.f, 0.f, 0.f, 0.f);
      if (nb + r < N) v = ((const float4*)(emb + (size_t)(nb + r) * EDIM))[c4];
      *(float4*)&sm[r][c4 * 4] = v;
    }
    __syncthreads();
    const int hq = threadIdx.x & 31;  // h-quad index = output plane
    const int h4 = hq * 4;
    const int rg = threadIdx.x >> 5;  // 8 groups of 4 rows
    float acc[4][4];
#pragma unroll
    for (int j = 0; j < 4; ++j)
#pragma unroll
      for (int q = 0; q < 4; ++q) acc[j][q] = 0.f;
    for (int e = 0; e < EDIM; e += 4) {
      float4 w[4];
#pragma unroll
      for (int q = 0; q < 4; ++q)
        w[q] = *(const float4*)(W2 + (size_t)(e + q) * HDIM + h4);
#pragma unroll
      for (int j = 0; j < 4; ++j) {
        float4 em = *(const float4*)&sm[rg * 4 + j][e];
        acc[j][0] = fmaf(em.x, w[0].x, acc[j][0]);
        acc[j][1] = fmaf(em.x, w[0].y, acc[j][1]);
        acc[j][2] = fmaf(em.x, w[0].z, acc[j][2]);
        acc[j][3] = fmaf(em.x, w[0].w, acc[j][3]);
        acc[j][0] = fmaf(em.y, w[1].x, acc[j][0]);
        acc[j][1] = fmaf(em.y, w[1].y, acc[j][1]);
        acc[j][2] = fmaf(em.y, w[1].z, acc[j][2]);
        acc[j][3] = fmaf(em.y, w[1].w, acc[j][3]);
        acc[j][0] = fmaf(em.z, w[2].x, acc[j][0]);
        acc[j][1] = fmaf(em.z, w[2].y, acc[j][1]);
        acc[j][2] = fmaf(em.z, w[2].z, acc[j][2]);
        acc[j][3] = fmaf(em.z, w[2].w, acc[j][3]);
        acc[j][0] = fmaf(em.w, w[3].x, acc[j][0]);
        acc[j][1] = fmaf(em.w, w[3].y, acc[j][1]);
        acc[j][2] = fmaf(em.w, w[3].z, acc[j][2]);
        acc[j][3] = fmaf(em.w, w[3].w, acc[j][3]);
      }
    }
    float4 bb2 = *(const float4*)(b2 + h4);
#pragma unroll
    for (int j = 0; j < 4; ++j) {
      int n = nb + rg * 4 + j;
      if (n < N) {
        float4 o;
        o.x = fexp2((acc[j][0] + bb2.x) * KSCALE);
        o.y = fexp2((acc[j][1] + bb2.y) * KSCALE);
        o.z = fexp2((acc[j][2] + bb2.z) * KSCALE);
        o.w = fexp2((acc[j][3] + bb2.w) * KSCALE);
        // transposed-packed store: plane hq, element n (L2 merges per-plane lines)
        *(float4*)(etpT4 + ((size_t)hq * npad + n) * 4) = o;
      }
    }
  } else {
    int t = ((int)blockIdx.x - nbTP) * 256 + threadIdx.x;
    if (t < BSES * HDIM) {
      int b = t >> 7, h = t & 127;
      const float* srow = sess + b * EDIM;
      float acc = 0.f;
#pragma unroll 4
      for (int e = 0; e < EDIM; ++e)
        acc = fmaf(srow[e], W1[e * HDIM + h], acc);
      esp[t] = fexp2((acc + b1[h]) * KSCALE);  // natural [b][h] layout
    }
    if (t == 0) {
      float s = b3[0];
      for (int i = 0; i < HDIM; ++i) s += W3[i];
      *C_out = s;
    }
  }
}

// Scoring: lane = target (64 targets/wave). Wave W -> tile = W/16, sessions
// (W%16)*4 .. +3. Per h-quarter: 8 coalesced dwordx4 et loads -> registers;
// esp rows + w3 are wave-uniform -> scalar loads (SGPR, off VALU path).
// Inner 4 sessions x 8 g4: pure register/SGPR VALU, 4 independent chains.
// No LDS, no barriers. score[b][n] = C - 2*sum_h w3[h]*rcp(fma(esp,etp,1))
__global__ __launch_bounds__(256) void taa_k2(
    const float* __restrict__ etpT4, const float* __restrict__ esp,
    const float* __restrict__ w3, const float* __restrict__ Cptr,
    float* __restrict__ out, int N, int npad) {
  const int lane = threadIdx.x & 63;
  const int wv = __builtin_amdgcn_readfirstlane((int)(threadIdx.x >> 6));
  const int W = blockIdx.x * 4 + wv;
  const int tile = W >> 4;
  const int s0 = (W & 15) * 4;
  const int n = tile * 64 + lane;  // always < npad (loads safe; store guarded)
  float acc[4] = {0.f, 0.f, 0.f, 0.f};
#pragma unroll 1
  for (int q = 0; q < 4; ++q) {
    float4 ev[8];
#pragma unroll
    for (int k = 0; k < 8; ++k)
      ev[k] = *(const float4*)(etpT4 + (((q << 3) + k) * (size_t)npad + n) * 4);
    const float* wq = w3 + (q << 5);  // uniform -> s_load
#pragma unroll
    for (int s = 0; s < 4; ++s) {
      const float* es = esp + (size_t)(s0 + s) * HDIM + (q << 5);  // uniform
#pragma unroll
      for (int k = 0; k < 8; ++k) {
        acc[s] = g4(es[4 * k + 0], es[4 * k + 1], es[4 * k + 2], es[4 * k + 3],
                    wq[4 * k + 0], wq[4 * k + 1], wq[4 * k + 2], wq[4 * k + 3],
                    ev[k], acc[s]);
      }
    }
  }
  const float Cv = *Cptr;  // uniform -> s_load
  if (n < N) {
#pragma unroll
    for (int s = 0; s < 4; ++s)
      out[(size_t)(s0 + s) * N + n] = fmaf(-2.f, acc[s], Cv);
  }
}

extern "C" void kernel_launch(void* const* d_in, const int* in_sizes, int n_in,
                              void* d_out, int out_size, void* d_ws, size_t ws_size,
                              hipStream_t stream) {
  const float* sess = (const float*)d_in[0];
  const float* emb  = (const float*)d_in[1];
  const float* W1   = (const float*)d_in[2];
  const float* b1   = (const float*)d_in[3];
  const float* W2   = (const float*)d_in[4];
  const float* b2   = (const float*)d_in[5];
  const float* W3   = (const float*)d_in[6];
  const float* b3   = (const float*)d_in[7];
  float* out = (float*)d_out;
  const int B = in_sizes[0] / EDIM;   // 64
  const int N = in_sizes[1] / EDIM;   // 20000

  const int tiles = (N + 63) / 64;    // 313
  const int npad = tiles * 64;        // 20032

  float* etpT4 = (float*)d_ws;                        // 128*npad floats
  float* esp   = etpT4 + (size_t)HDIM * npad;         // B*128 floats
  float* Cp    = esp + (size_t)BSES * HDIM;           // 1 float

  const int nbTP = (N + 31) / 32;                     // 625
  const int nbSP = (B * HDIM + 255) / 256;            // 32
  taa_k1<<<nbTP + nbSP, 256, 0, stream>>>(sess, W1, b1, emb, W2, b2, W3, b3,
                                          etpT4, esp, Cp, N, npad, nbTP);
  // tiles*16 waves total (16 session-groups of 4 per tile), 4 waves/block.
  taa_k2<<<tiles * 4, 256, 0, stream>>>(etpT4, esp, W3, Cp, out, N, npad);
}